// Round 1
// baseline (889.294 us; speedup 1.0000x reference)
//
#include <hip/hip_runtime.h>
#include <math.h>

#define B_ROWS 131072
#define ROWS 128
#define XP 68   // Xs pitch (floats): 16B-aligned; row stride ≡ 4 mod 32 words -> uniform bank quartets
#define MP 68   // Ms pitch
#define LP 34   // Ls pitch (scalar access only)

// ---------------- precompute M = [Wr*Wp | 0.1*Wr ; Wn*Wp | 0.1*Wn], c = bias ----
__global__ void precompute_M(const float* __restrict__ Wp,
                             const float* __restrict__ Wr,
                             const float* __restrict__ Wn,
                             const float* __restrict__ bp,
                             const float* __restrict__ br,
                             const float* __restrict__ bn,
                             float* __restrict__ M,
                             float* __restrict__ c) {
  int o = blockIdx.x * 256 + threadIdx.x;          // 32*1024 outputs
  if (o < 32 * 1024) {
    int j = o >> 10, k = o & 1023;
    const float* W = (j < 16) ? Wr : Wn;
    int jj = j & 15;
    float v;
    if (k < 768) {
      double s = 0.0;
      for (int d = 0; d < 256; ++d)
        s += (double)W[jj * 256 + d] * (double)Wp[d * 768 + k];
      v = (float)s;
    } else {
      v = 0.1f * W[jj * 256 + (k - 768)];
    }
    M[o] = v;
  }
  if (blockIdx.x == 0 && threadIdx.x < 32) {
    int j = threadIdx.x, jj = j & 15;
    const float* W = (j < 16) ? Wr : Wn;
    const float* b = (j < 16) ? br : bn;
    double s = (double)b[jj];
    for (int d = 0; d < 256; ++d)
      s += (double)W[jj * 256 + d] * (double)bp[d];
    c[j] = (float)s;
  }
}

// ---------------- main fused kernel ------------------------------------------
__global__ __launch_bounds__(256, 3)
void router_main(const float* __restrict__ zn, const float* __restrict__ zs,
                 const float* __restrict__ zt, const float* __restrict__ nz,
                 const float* __restrict__ nr, const int* __restrict__ patches,
                 const float* __restrict__ M, const float* __restrict__ c,
                 float* __restrict__ out) {
  __shared__ float smem[ROWS * XP + 32 * MP];   // 43.5 KB
  float* const Xs = smem;                       // [128][XP] : 64-k X tile
  float* const Ms = smem + ROWS * XP;           // [32][MP]  : 64-k M tile
  float* const Ls = smem;                       // aliases Xs (dead after main loop)

  const int t = threadIdx.x;
  const int row0 = blockIdx.x * ROWS;
  const int jg = t & 7;     // j = jg + 8*jj  (stride-8 -> conflict-free b128)
  const int rg = t >> 3;    // r = rg + 32*rr (in-wave rg 0..7 -> conflict-free)
  const int sr = t >> 3;    // staging row
  const int sk4 = t & 7;    // staging k-quad

  float accf[4][4];
  double accd[4][4];
#pragma unroll
  for (int a = 0; a < 4; ++a)
#pragma unroll
    for (int b = 0; b < 4; ++b) { accf[a][b] = 0.f; accd[a][b] = 0.0; }

  // register double-buffer: loads for stage s+1 issued before compute of stage s
  float4 xg[8], mg[2];

  auto load_stage = [&](int s) {
    const int k0 = s * 64;
    const float* src; int col0;
    if (k0 < 256)      { src = zn; col0 = k0; }
    else if (k0 < 512) { src = zs; col0 = k0 - 256; }
    else if (k0 < 768) { src = zt; col0 = k0 - 512; }
    else               { src = nz; col0 = k0 - 768; }
#pragma unroll
    for (int i = 0; i < 4; ++i) {
      const float* p = &src[(size_t)(row0 + sr + 32 * i) * 256 + col0 + 4 * sk4];
      xg[2 * i]     = *(const float4*)p;
      xg[2 * i + 1] = *(const float4*)(p + 32);
    }
    const float* q = &M[(size_t)sr * 1024 + k0 + 4 * sk4];
    mg[0] = *(const float4*)q;
    mg[1] = *(const float4*)(q + 32);
  };

  load_stage(0);   // prologue

  for (int s = 0; s < 16; ++s) {
    __syncthreads();   // previous iteration's LDS reads done
#pragma unroll
    for (int i = 0; i < 4; ++i) {
      *(float4*)&Xs[(sr + 32 * i) * XP + 4 * sk4]      = xg[2 * i];
      *(float4*)&Xs[(sr + 32 * i) * XP + 4 * sk4 + 32] = xg[2 * i + 1];
    }
    *(float4*)&Ms[sr * MP + 4 * sk4]      = mg[0];
    *(float4*)&Ms[sr * MP + 4 * sk4 + 32] = mg[1];
    __syncthreads();

    // issue next stage's loads NOW: ~2000 cyc of FMAs below hide HBM latency
    if (s < 15) load_stage(s + 1);

#pragma unroll
    for (int ks = 0; ks < 16; ++ks) {
      const int k = 4 * ks;
      float4 m4[4], x4[4];
#pragma unroll
      for (int jj = 0; jj < 4; ++jj)
        m4[jj] = *(const float4*)&Ms[(jg + 8 * jj) * MP + k];
#pragma unroll
      for (int rr = 0; rr < 4; ++rr)
        x4[rr] = *(const float4*)&Xs[(rg + 32 * rr) * XP + k];
#pragma unroll
      for (int jj = 0; jj < 4; ++jj)
#pragma unroll
        for (int rr = 0; rr < 4; ++rr) {
          accf[jj][rr] += m4[jj].x * x4[rr].x;
          accf[jj][rr] += m4[jj].y * x4[rr].y;
          accf[jj][rr] += m4[jj].z * x4[rr].z;
          accf[jj][rr] += m4[jj].w * x4[rr].w;
        }
      // fold each 32-k chunk into f64 accumulator (same cadence as 602µs version:
      // keeps error ~3e-8 vs exact so top-k indices match reference)
      if (ks == 7 || ks == 15) {
#pragma unroll
        for (int jj = 0; jj < 4; ++jj)
#pragma unroll
          for (int rr = 0; rr < 4; ++rr) { accd[jj][rr] += (double)accf[jj][rr]; accf[jj][rr] = 0.f; }
      }
    }
  }

  __syncthreads();   // all Xs reads complete before Ls (aliased) is written

  // gather the 32 pre-activation logits per row into LDS
#pragma unroll
  for (int jj = 0; jj < 4; ++jj) {
    const int j = jg + 8 * jj;
    const float cj = c[j];
#pragma unroll
    for (int rr = 0; rr < 4; ++rr) {
      const int r = rg + 32 * rr;
      Ls[r * LP + j] = (float)(accd[jj][rr] + (double)cj);
    }
  }
  __syncthreads();

  if (t < ROWS) {
    const int row = row0 + t;
    float L[32];
#pragma unroll
    for (int j = 0; j < 32; ++j) L[j] = Ls[t * LP + j];

    float nrv[16];
#pragma unroll
    for (int q = 0; q < 4; ++q) {
      float4 v = *(const float4*)&nr[(size_t)row * 16 + 4 * q];
      nrv[4 * q] = v.x; nrv[4 * q + 1] = v.y; nrv[4 * q + 2] = v.z; nrv[4 * q + 3] = v.w;
    }

    float lg[16];
#pragma unroll
    for (int p = 0; p < 16; ++p) {
      const float x = L[16 + p];
      const float sp = (x > 15.f) ? x : log1pf(expf(x));   // softplus
      lg[p] = L[p] + nrv[p] * sp;
    }

    float mx = lg[0];
#pragma unroll
    for (int p = 1; p < 16; ++p) mx = fmaxf(mx, lg[p]);
    float e[16]; float sum = 0.f;
#pragma unroll
    for (int p = 0; p < 16; ++p) { e[p] = expf(lg[p] - mx); sum += e[p]; }
    float w[16];
#pragma unroll
    for (int p = 0; p < 16; ++p) w[p] = e[p] / sum;

    // top-4, strict > scan => lowest index wins ties (jax.lax.top_k semantics)
    int idx[4]; float val[4]; unsigned used = 0;
#pragma unroll
    for (int kk = 0; kk < 4; ++kk) {
      float best = -1.f; int bi = 0;
#pragma unroll
      for (int p = 0; p < 16; ++p) {
        const bool ok = (((used >> p) & 1u) == 0u) && (w[p] > best);
        best = ok ? w[p] : best;
        bi = ok ? p : bi;
      }
      idx[kk] = bi; val[kk] = best; used |= (1u << bi);
    }

    float so[16];
#pragma unroll
    for (int p = 0; p < 16; ++p) {
      float v = 0.f;
#pragma unroll
      for (int kk = 0; kk < 4; ++kk) v = (idx[kk] == p) ? val[kk] : v;
      so[p] = v;
    }
#pragma unroll
    for (int q = 0; q < 4; ++q)
      *(float4*)&out[(size_t)row * 16 + 4 * q] =
          make_float4(so[4 * q], so[4 * q + 1], so[4 * q + 2], so[4 * q + 3]);

    float4 pv, iv;
    pv.x = (float)patches[idx[0]]; pv.y = (float)patches[idx[1]];
    pv.z = (float)patches[idx[2]]; pv.w = (float)patches[idx[3]];
    iv.x = (float)idx[0]; iv.y = (float)idx[1];
    iv.z = (float)idx[2]; iv.w = (float)idx[3];
    *(float4*)&out[(size_t)B_ROWS * 16 + (size_t)row * 4] = pv;
    *(float4*)&out[(size_t)B_ROWS * 20 + (size_t)row * 4] = iv;
  }
}

// ---------------- launcher ---------------------------------------------------
extern "C" void kernel_launch(void* const* d_in, const int* in_sizes, int n_in,
                              void* d_out, int out_size, void* d_ws, size_t ws_size,
                              hipStream_t stream) {
  const float* zn = (const float*)d_in[0];
  const float* zs = (const float*)d_in[1];
  const float* zt = (const float*)d_in[2];
  const float* nz = (const float*)d_in[3];
  const float* nr = (const float*)d_in[4];
  const int*   pc = (const int*)d_in[5];
  const float* Wp = (const float*)d_in[6];
  const float* bp = (const float*)d_in[7];
  const float* Wr = (const float*)d_in[8];
  const float* br = (const float*)d_in[9];
  const float* Wn = (const float*)d_in[10];
  const float* bn = (const float*)d_in[11];
  float* out = (float*)d_out;
  float* M = (float*)d_ws;            // 32*1024 floats
  float* c = M + 32 * 1024;           // 32 floats

  precompute_M<<<128, 256, 0, stream>>>(Wp, Wr, Wn, bp, br, bn, M, c);
  router_main<<<B_ROWS / ROWS, 256, 0, stream>>>(zn, zs, zt, nz, nr, pc, M, c, out);
}

// Round 5
// 617.702 us; speedup vs baseline: 1.4397x; 1.4397x over previous
//
#include <hip/hip_runtime.h>
#include <math.h>

#define B_ROWS 131072
#define ROWS 128
#define XP 36   // Xs pitch (floats): 16B-aligned, bank-staggered (stride ≡ 4 mod 32 words)
#define MP 36   // Ms pitch
#define LP 34   // Ls pitch (scalar access only)

// ---------------- precompute M = [Wr*Wp | 0.1*Wr ; Wn*Wp | 0.1*Wn], c = bias ----
__global__ void precompute_M(const float* __restrict__ Wp,
                             const float* __restrict__ Wr,
                             const float* __restrict__ Wn,
                             const float* __restrict__ bp,
                             const float* __restrict__ br,
                             const float* __restrict__ bn,
                             float* __restrict__ M,
                             float* __restrict__ c) {
  int o = blockIdx.x * 256 + threadIdx.x;          // 32*1024 outputs
  if (o < 32 * 1024) {
    int j = o >> 10, k = o & 1023;
    const float* W = (j < 16) ? Wr : Wn;
    int jj = j & 15;
    float v;
    if (k < 768) {
      double s = 0.0;
      for (int d = 0; d < 256; ++d)
        s += (double)W[jj * 256 + d] * (double)Wp[d * 768 + k];
      v = (float)s;
    } else {
      v = 0.1f * W[jj * 256 + (k - 768)];
    }
    M[o] = v;
  }
  if (blockIdx.x == 0 && threadIdx.x < 32) {
    int j = threadIdx.x, jj = j & 15;
    const float* W = (j < 16) ? Wr : Wn;
    const float* b = (j < 16) ? br : bn;
    double s = (double)b[jj];
    for (int d = 0; d < 256; ++d)
      s += (double)W[jj * 256 + d] * (double)bp[d];
    c[j] = (float)s;
  }
}

// ---------------- main fused kernel ------------------------------------------
__global__ __launch_bounds__(256, 3)
void router_main(const float* __restrict__ zn, const float* __restrict__ zs,
                 const float* __restrict__ zt, const float* __restrict__ nz,
                 const float* __restrict__ nr, const int* __restrict__ patches,
                 const float* __restrict__ M, const float* __restrict__ c,
                 float* __restrict__ out) {
  __shared__ float Xs[ROWS * XP];   // 18.0 KB  (also reused as Ls after main loop)
  __shared__ float Ms[32 * MP];     //  4.5 KB
  float* const Ls = Xs;             // alias: Xs dead after main loop; 128*34=4352 <= 128*36=4608

  const int t = threadIdx.x;
  const int row0 = blockIdx.x * ROWS;
  const int jg = t & 7;     // j = jg + 8*jj  (stride-8 -> conflict-free b128)
  const int rg = t >> 3;    // r = rg + 32*rr (in-wave rg 0..7 -> conflict-free)
  const int sr = t >> 3;    // staging row
  const int sk4 = t & 7;    // staging k-quad

  float accf[4][4];
  double accd[4][4];
#pragma unroll
  for (int a = 0; a < 4; ++a)
#pragma unroll
    for (int b = 0; b < 4; ++b) { accf[a][b] = 0.f; accd[a][b] = 0.0; }

  // one-stage-ahead register pipeline: only 5 float4 (20 VGPR) in flight
  float4 xg[4], mg;

  auto load_stage = [&](int s) {
    const int k0 = s * 32;
    const float* src; int col0;
    if (k0 < 256)      { src = zn; col0 = k0; }
    else if (k0 < 512) { src = zs; col0 = k0 - 256; }
    else if (k0 < 768) { src = zt; col0 = k0 - 512; }
    else               { src = nz; col0 = k0 - 768; }
#pragma unroll
    for (int i = 0; i < 4; ++i)
      xg[i] = *(const float4*)&src[(size_t)(row0 + sr + 32 * i) * 256 + col0 + 4 * sk4];
    mg = *(const float4*)&M[(size_t)sr * 1024 + k0 + 4 * sk4];
  };

  load_stage(0);   // prologue

  for (int s = 0; s < 32; ++s) {
    __syncthreads();   // previous iteration's LDS reads done
#pragma unroll
    for (int i = 0; i < 4; ++i)
      *(float4*)&Xs[(sr + 32 * i) * XP + 4 * sk4] = xg[i];
    *(float4*)&Ms[sr * MP + 4 * sk4] = mg;
    __syncthreads();

    // issue next stage's loads NOW: full compute phase below hides HBM latency
    if (s < 31) load_stage(s + 1);

#pragma unroll
    for (int ks = 0; ks < 8; ++ks) {
      const int k = 4 * ks;
      float4 m4[4], x4[4];
#pragma unroll
      for (int jj = 0; jj < 4; ++jj)
        m4[jj] = *(const float4*)&Ms[(jg + 8 * jj) * MP + k];
#pragma unroll
      for (int rr = 0; rr < 4; ++rr)
        x4[rr] = *(const float4*)&Xs[(rg + 32 * rr) * XP + k];
#pragma unroll
      for (int jj = 0; jj < 4; ++jj)
#pragma unroll
        for (int rr = 0; rr < 4; ++rr) {
          accf[jj][rr] += m4[jj].x * x4[rr].x;
          accf[jj][rr] += m4[jj].y * x4[rr].y;
          accf[jj][rr] += m4[jj].z * x4[rr].z;
          accf[jj][rr] += m4[jj].w * x4[rr].w;
        }
    }
    // fold 32-k chunk into f64 accumulator (keeps error ~3e-8 vs exact)
#pragma unroll
    for (int jj = 0; jj < 4; ++jj)
#pragma unroll
      for (int rr = 0; rr < 4; ++rr) { accd[jj][rr] += (double)accf[jj][rr]; accf[jj][rr] = 0.f; }
  }

  __syncthreads();   // all Xs reads complete before Ls (aliased) is written

  // gather the 32 pre-activation logits per row into LDS
#pragma unroll
  for (int jj = 0; jj < 4; ++jj) {
    const int j = jg + 8 * jj;
    const float cj = c[j];
#pragma unroll
    for (int rr = 0; rr < 4; ++rr) {
      const int r = rg + 32 * rr;
      Ls[r * LP + j] = (float)(accd[jj][rr] + (double)cj);
    }
  }
  __syncthreads();

  if (t < ROWS) {
    const int row = row0 + t;
    float L[32];
#pragma unroll
    for (int j = 0; j < 32; ++j) L[j] = Ls[t * LP + j];

    float nrv[16];
#pragma unroll
    for (int q = 0; q < 4; ++q) {
      float4 v = *(const float4*)&nr[(size_t)row * 16 + 4 * q];
      nrv[4 * q] = v.x; nrv[4 * q + 1] = v.y; nrv[4 * q + 2] = v.z; nrv[4 * q + 3] = v.w;
    }

    float lg[16];
#pragma unroll
    for (int p = 0; p < 16; ++p) {
      const float x = L[16 + p];
      const float sp = (x > 15.f) ? x : log1pf(expf(x));   // softplus
      lg[p] = L[p] + nrv[p] * sp;
    }

    float mx = lg[0];
#pragma unroll
    for (int p = 1; p < 16; ++p) mx = fmaxf(mx, lg[p]);
    float e[16]; float sum = 0.f;
#pragma unroll
    for (int p = 0; p < 16; ++p) { e[p] = expf(lg[p] - mx); sum += e[p]; }
    float w[16];
#pragma unroll
    for (int p = 0; p < 16; ++p) w[p] = e[p] / sum;

    // top-4, strict > scan => lowest index wins ties (jax.lax.top_k semantics)
    int idx[4]; float val[4]; unsigned used = 0;
#pragma unroll
    for (int kk = 0; kk < 4; ++kk) {
      float best = -1.f; int bi = 0;
#pragma unroll
      for (int p = 0; p < 16; ++p) {
        const bool ok = (((used >> p) & 1u) == 0u) && (w[p] > best);
        best = ok ? w[p] : best;
        bi = ok ? p : bi;
      }
      idx[kk] = bi; val[kk] = best; used |= (1u << bi);
    }

    float so[16];
#pragma unroll
    for (int p = 0; p < 16; ++p) {
      float v = 0.f;
#pragma unroll
      for (int kk = 0; kk < 4; ++kk) v = (idx[kk] == p) ? val[kk] : v;
      so[p] = v;
    }
#pragma unroll
    for (int q = 0; q < 4; ++q)
      *(float4*)&out[(size_t)row * 16 + 4 * q] =
          make_float4(so[4 * q], so[4 * q + 1], so[4 * q + 2], so[4 * q + 3]);

    float4 pv, iv;
    pv.x = (float)patches[idx[0]]; pv.y = (float)patches[idx[1]];
    pv.z = (float)patches[idx[2]]; pv.w = (float)patches[idx[3]];
    iv.x = (float)idx[0]; iv.y = (float)idx[1];
    iv.z = (float)idx[2]; iv.w = (float)idx[3];
    *(float4*)&out[(size_t)B_ROWS * 16 + (size_t)row * 4] = pv;
    *(float4*)&out[(size_t)B_ROWS * 20 + (size_t)row * 4] = iv;
  }
}

// ---------------- launcher ---------------------------------------------------
extern "C" void kernel_launch(void* const* d_in, const int* in_sizes, int n_in,
                              void* d_out, int out_size, void* d_ws, size_t ws_size,
                              hipStream_t stream) {
  const float* zn = (const float*)d_in[0];
  const float* zs = (const float*)d_in[1];
  const float* zt = (const float*)d_in[2];
  const float* nz = (const float*)d_in[3];
  const float* nr = (const float*)d_in[4];
  const int*   pc = (const int*)d_in[5];
  const float* Wp = (const float*)d_in[6];
  const float* bp = (const float*)d_in[7];
  const float* Wr = (const float*)d_in[8];
  const float* br = (const float*)d_in[9];
  const float* Wn = (const float*)d_in[10];
  const float* bn = (const float*)d_in[11];
  float* out = (float*)d_out;
  float* M = (float*)d_ws;            // 32*1024 floats
  float* c = M + 32 * 1024;           // 32 floats

  precompute_M<<<128, 256, 0, stream>>>(Wp, Wr, Wn, bp, br, bn, M, c);
  router_main<<<B_ROWS / ROWS, 256, 0, stream>>>(zn, zs, zt, nz, nr, pc, M, c, out);
}

// Round 7
// 529.650 us; speedup vs baseline: 1.6790x; 1.1662x over previous
//
#include <hip/hip_runtime.h>
#include <math.h>

#define B_ROWS 131072
#define ROWS 128
#define XP 36   // Xs pitch (floats): 16B-aligned, bank-staggered (stride ≡ 4 mod 32 words)
#define MP 36   // Ms pitch
#define LP 34   // Ls pitch (scalar access only)

// ---------------- precompute M = [Wr*Wp | 0.1*Wr ; Wn*Wp | 0.1*Wn], c = bias ----
__global__ void precompute_M(const float* __restrict__ Wp,
                             const float* __restrict__ Wr,
                             const float* __restrict__ Wn,
                             const float* __restrict__ bp,
                             const float* __restrict__ br,
                             const float* __restrict__ bn,
                             float* __restrict__ M,
                             float* __restrict__ c) {
  int o = blockIdx.x * 256 + threadIdx.x;          // 32*1024 outputs
  if (o < 32 * 1024) {
    int j = o >> 10, k = o & 1023;
    const float* W = (j < 16) ? Wr : Wn;
    int jj = j & 15;
    float v;
    if (k < 768) {
      // 4 independent f64 chains: breaks the serial fma dependency (ILP x4)
      double s0 = 0.0, s1 = 0.0, s2 = 0.0, s3 = 0.0;
      for (int d = 0; d < 256; d += 4) {
        s0 += (double)W[jj * 256 + d]     * (double)Wp[(d)     * 768 + k];
        s1 += (double)W[jj * 256 + d + 1] * (double)Wp[(d + 1) * 768 + k];
        s2 += (double)W[jj * 256 + d + 2] * (double)Wp[(d + 2) * 768 + k];
        s3 += (double)W[jj * 256 + d + 3] * (double)Wp[(d + 3) * 768 + k];
      }
      v = (float)((s0 + s1) + (s2 + s3));
    } else {
      v = 0.1f * W[jj * 256 + (k - 768)];
    }
    M[o] = v;
  }
  if (blockIdx.x == 0 && threadIdx.x < 32) {
    int j = threadIdx.x, jj = j & 15;
    const float* W = (j < 16) ? Wr : Wn;
    const float* b = (j < 16) ? br : bn;
    double s = (double)b[jj];
    for (int d = 0; d < 256; ++d)
      s += (double)W[jj * 256 + d] * (double)bp[d];
    c[j] = (float)s;
  }
}

// ---------------- main fused kernel ------------------------------------------
// Staging lives in NAMED scalar float4s written by a macro (no lambda, no
// address-taken arrays): guarantees register residency. Round-5 counters
// showed VGPR=68 (= accumulators+staging exactly) + 284 MB scratch writes —
// signature of the [&]-captured xg[]/mg failing SROA promotion.
#define LOAD_STAGE(S_) do {                                                   \
    const int k0_ = (S_) * 32;                                                \
    const float* src_; int col0_;                                             \
    if (k0_ < 256)      { src_ = zn; col0_ = k0_; }                           \
    else if (k0_ < 512) { src_ = zs; col0_ = k0_ - 256; }                     \
    else if (k0_ < 768) { src_ = zt; col0_ = k0_ - 512; }                     \
    else                { src_ = nz; col0_ = k0_ - 768; }                     \
    const float* base_ = src_ + (size_t)(row0 + sr) * 256 + col0_ + 4 * sk4;  \
    xg0 = *(const float4*)(base_);                                            \
    xg1 = *(const float4*)(base_ + 32 * 256);                                 \
    xg2 = *(const float4*)(base_ + 64 * 256);                                 \
    xg3 = *(const float4*)(base_ + 96 * 256);                                 \
    mg  = *(const float4*)&M[(size_t)sr * 1024 + k0_ + 4 * sk4];              \
  } while (0)

__global__ __launch_bounds__(256, 3)
void router_main(const float* __restrict__ zn, const float* __restrict__ zs,
                 const float* __restrict__ zt, const float* __restrict__ nz,
                 const float* __restrict__ nr, const int* __restrict__ patches,
                 const float* __restrict__ M, const float* __restrict__ c,
                 float* __restrict__ out) {
  __shared__ float Xs[ROWS * XP];   // 18.0 KB  (also reused as Ls after main loop)
  __shared__ float Ms[32 * MP];     //  4.5 KB
  float* const Ls = Xs;             // alias: Xs dead after main loop; 128*34=4352 <= 128*36=4608

  const int t = threadIdx.x;
  const int row0 = blockIdx.x * ROWS;
  const int jg = t & 7;     // j = jg + 8*jj  (stride-8 -> conflict-free b128)
  const int rg = t >> 3;    // r = rg + 32*rr (in-wave rg 0..7 -> conflict-free)
  const int sr = t >> 3;    // staging row
  const int sk4 = t & 7;    // staging k-quad

  float accf[4][4];
  double accd[4][4];
#pragma unroll
  for (int a = 0; a < 4; ++a)
#pragma unroll
    for (int b = 0; b < 4; ++b) { accf[a][b] = 0.f; accd[a][b] = 0.0; }

  // one-stage-ahead register pipeline: 5 float4 (20 VGPR) in flight
  float4 xg0, xg1, xg2, xg3, mg;

  LOAD_STAGE(0);   // prologue

  for (int s = 0; s < 32; ++s) {
    __syncthreads();   // previous iteration's LDS reads done
    *(float4*)&Xs[(sr +  0) * XP + 4 * sk4] = xg0;
    *(float4*)&Xs[(sr + 32) * XP + 4 * sk4] = xg1;
    *(float4*)&Xs[(sr + 64) * XP + 4 * sk4] = xg2;
    *(float4*)&Xs[(sr + 96) * XP + 4 * sk4] = xg3;
    *(float4*)&Ms[sr * MP + 4 * sk4] = mg;
    __syncthreads();

    // issue next stage's loads NOW: full compute phase below hides HBM latency
    if (s < 31) LOAD_STAGE(s + 1);

#pragma unroll
    for (int ks = 0; ks < 8; ++ks) {
      const int k = 4 * ks;
      float4 m4[4], x4[4];
#pragma unroll
      for (int jj = 0; jj < 4; ++jj)
        m4[jj] = *(const float4*)&Ms[(jg + 8 * jj) * MP + k];
#pragma unroll
      for (int rr = 0; rr < 4; ++rr)
        x4[rr] = *(const float4*)&Xs[(rg + 32 * rr) * XP + k];
#pragma unroll
      for (int jj = 0; jj < 4; ++jj)
#pragma unroll
        for (int rr = 0; rr < 4; ++rr) {
          accf[jj][rr] += m4[jj].x * x4[rr].x;
          accf[jj][rr] += m4[jj].y * x4[rr].y;
          accf[jj][rr] += m4[jj].z * x4[rr].z;
          accf[jj][rr] += m4[jj].w * x4[rr].w;
        }
    }
    // fold 32-k chunk into f64 accumulator (keeps error ~3e-8 vs exact)
#pragma unroll
    for (int jj = 0; jj < 4; ++jj)
#pragma unroll
      for (int rr = 0; rr < 4; ++rr) { accd[jj][rr] += (double)accf[jj][rr]; accf[jj][rr] = 0.f; }
  }

  __syncthreads();   // all Xs reads complete before Ls (aliased) is written

  // gather the 32 pre-activation logits per row into LDS
#pragma unroll
  for (int jj = 0; jj < 4; ++jj) {
    const int j = jg + 8 * jj;
    const float cj = c[j];
#pragma unroll
    for (int rr = 0; rr < 4; ++rr) {
      const int r = rg + 32 * rr;
      Ls[r * LP + j] = (float)(accd[jj][rr] + (double)cj);
    }
  }
  __syncthreads();

  if (t < ROWS) {
    const int row = row0 + t;
    float L[32];
#pragma unroll
    for (int j = 0; j < 32; ++j) L[j] = Ls[t * LP + j];

    float nrv[16];
#pragma unroll
    for (int q = 0; q < 4; ++q) {
      float4 v = *(const float4*)&nr[(size_t)row * 16 + 4 * q];
      nrv[4 * q] = v.x; nrv[4 * q + 1] = v.y; nrv[4 * q + 2] = v.z; nrv[4 * q + 3] = v.w;
    }

    float lg[16];
#pragma unroll
    for (int p = 0; p < 16; ++p) {
      const float x = L[16 + p];
      const float sp = (x > 15.f) ? x : log1pf(expf(x));   // softplus
      lg[p] = L[p] + nrv[p] * sp;
    }

    float mx = lg[0];
#pragma unroll
    for (int p = 1; p < 16; ++p) mx = fmaxf(mx, lg[p]);
    float e[16]; float sum = 0.f;
#pragma unroll
    for (int p = 0; p < 16; ++p) { e[p] = expf(lg[p] - mx); sum += e[p]; }
    float w[16];
#pragma unroll
    for (int p = 0; p < 16; ++p) w[p] = e[p] / sum;

    // top-4, strict > scan => lowest index wins ties (jax.lax.top_k semantics)
    int idx[4]; float val[4]; unsigned used = 0;
#pragma unroll
    for (int kk = 0; kk < 4; ++kk) {
      float best = -1.f; int bi = 0;
#pragma unroll
      for (int p = 0; p < 16; ++p) {
        const bool ok = (((used >> p) & 1u) == 0u) && (w[p] > best);
        best = ok ? w[p] : best;
        bi = ok ? p : bi;
      }
      idx[kk] = bi; val[kk] = best; used |= (1u << bi);
    }

    float so[16];
#pragma unroll
    for (int p = 0; p < 16; ++p) {
      float v = 0.f;
#pragma unroll
      for (int kk = 0; kk < 4; ++kk) v = (idx[kk] == p) ? val[kk] : v;
      so[p] = v;
    }
#pragma unroll
    for (int q = 0; q < 4; ++q)
      *(float4*)&out[(size_t)row * 16 + 4 * q] =
          make_float4(so[4 * q], so[4 * q + 1], so[4 * q + 2], so[4 * q + 3]);

    float4 pv, iv;
    pv.x = (float)patches[idx[0]]; pv.y = (float)patches[idx[1]];
    pv.z = (float)patches[idx[2]]; pv.w = (float)patches[idx[3]];
    iv.x = (float)idx[0]; iv.y = (float)idx[1];
    iv.z = (float)idx[2]; iv.w = (float)idx[3];
    *(float4*)&out[(size_t)B_ROWS * 16 + (size_t)row * 4] = pv;
    *(float4*)&out[(size_t)B_ROWS * 20 + (size_t)row * 4] = iv;
  }
}

// ---------------- launcher ---------------------------------------------------
extern "C" void kernel_launch(void* const* d_in, const int* in_sizes, int n_in,
                              void* d_out, int out_size, void* d_ws, size_t ws_size,
                              hipStream_t stream) {
  const float* zn = (const float*)d_in[0];
  const float* zs = (const float*)d_in[1];
  const float* zt = (const float*)d_in[2];
  const float* nz = (const float*)d_in[3];
  const float* nr = (const float*)d_in[4];
  const int*   pc = (const int*)d_in[5];
  const float* Wp = (const float*)d_in[6];
  const float* bp = (const float*)d_in[7];
  const float* Wr = (const float*)d_in[8];
  const float* br = (const float*)d_in[9];
  const float* Wn = (const float*)d_in[10];
  const float* bn = (const float*)d_in[11];
  float* out = (float*)d_out;
  float* M = (float*)d_ws;            // 32*1024 floats
  float* c = M + 32 * 1024;           // 32 floats

  precompute_M<<<128, 256, 0, stream>>>(Wp, Wr, Wn, bp, br, bn, M, c);
  router_main<<<B_ROWS / ROWS, 256, 0, stream>>>(zn, zs, zt, nz, nr, pc, M, c, out);
}

// Round 14
// 501.324 us; speedup vs baseline: 1.7739x; 1.0565x over previous
//
#include <hip/hip_runtime.h>
#include <math.h>

#define B_ROWS 131072
#define ROWS 128
#define XPB 40   // bf16 pitch for LDS tiles: 80 B rows
#define LP 34    // Ls pitch (f32, scalar access only)

typedef __attribute__((ext_vector_type(8))) short short8v;   // 8 bf16 = MFMA A/B frag
typedef __attribute__((ext_vector_type(4))) short short4v;   // 4 bf16 = b64 store
typedef __attribute__((ext_vector_type(4))) float float4v;   // MFMA C/D frag

__device__ __forceinline__ short f2bf(float x) {            // RNE f32 -> bf16 bits
  unsigned u = __builtin_bit_cast(unsigned, x);
  u += 0x7fffu + ((u >> 16) & 1u);
  return (short)(u >> 16);
}
__device__ __forceinline__ float bf2f(short h) {
  unsigned u = ((unsigned)(unsigned short)h) << 16;
  return __builtin_bit_cast(float, u);
}

// ---- precompute M = [Wr*Wp | 0.1*Wr ; Wn*Wp | 0.1*Wn] (f32), c = bias --------
__global__ void precompute_M(const float* __restrict__ Wp,
                             const float* __restrict__ Wr,
                             const float* __restrict__ Wn,
                             const float* __restrict__ bp,
                             const float* __restrict__ br,
                             const float* __restrict__ bn,
                             float* __restrict__ M,
                             float* __restrict__ c) {
  int o = blockIdx.x * 256 + threadIdx.x;          // 32*1024 outputs
  if (o < 32 * 1024) {
    int j = o >> 10, k = o & 1023;
    const float* W = (j < 16) ? Wr : Wn;
    int jj = j & 15;
    float v;
    if (k < 768) {
      double s0 = 0.0, s1 = 0.0, s2 = 0.0, s3 = 0.0;
      for (int d = 0; d < 256; d += 4) {
        s0 += (double)W[jj * 256 + d]     * (double)Wp[(d)     * 768 + k];
        s1 += (double)W[jj * 256 + d + 1] * (double)Wp[(d + 1) * 768 + k];
        s2 += (double)W[jj * 256 + d + 2] * (double)Wp[(d + 2) * 768 + k];
        s3 += (double)W[jj * 256 + d + 3] * (double)Wp[(d + 3) * 768 + k];
      }
      v = (float)((s0 + s1) + (s2 + s3));
    } else {
      v = 0.1f * W[jj * 256 + (k - 768)];
    }
    M[o] = v;
  }
  if (blockIdx.x == 0 && threadIdx.x < 32) {
    int j = threadIdx.x, jj = j & 15;
    const float* W = (j < 16) ? Wr : Wn;
    const float* b = (j < 16) ? br : bn;
    double s = (double)b[jj];
    for (int d = 0; d < 256; ++d)
      s += (double)W[jj * 256 + d] * (double)bp[d];
    c[j] = (float)s;
  }
}

// ------------- main fused kernel (MFMA 3-way-split-bf16 GEMM core) ------------
// Round-10 lesson: 2-way split (err ~1.4e-6) flips near-tie top-k rows.
// 3-way split (24-bit coverage) + 6 products + per-stage f64 fold reproduces
// round-7's passing error budget (~4e-8) on the MFMA pipe.
// All staging in NAMED scalars (round-5/7 lesson: lambda-captured arrays spill).
#define LOAD_STAGE(S_) do {                                                   \
    const int k0_ = (S_) * 32;                                                \
    const float* src_; int col0_;                                             \
    if (k0_ < 256)      { src_ = zn; col0_ = k0_; }                           \
    else if (k0_ < 512) { src_ = zs; col0_ = k0_ - 256; }                     \
    else if (k0_ < 768) { src_ = zt; col0_ = k0_ - 512; }                     \
    else                { src_ = nz; col0_ = k0_ - 768; }                     \
    const float* base_ = src_ + (size_t)(row0 + sr) * 256 + col0_ + 4 * sk4;  \
    xg0 = *(const float4*)(base_);                                            \
    xg1 = *(const float4*)(base_ + 32 * 256);                                 \
    xg2 = *(const float4*)(base_ + 64 * 256);                                 \
    xg3 = *(const float4*)(base_ + 96 * 256);                                 \
    mg  = *(const float4*)&M[(size_t)sr * 1024 + k0_ + 4 * sk4];              \
  } while (0)

// 3-way split of 4 f32 -> 3 bf16 planes (h: top 8 mantissa bits, m: next 8, l: next 8)
#define CVT3(VG_, PH_, PM_, PL_, OFF_) do {                                   \
    short4v h_, m_, l_;                                                       \
    float v_, r_;                                                             \
    v_ = VG_.x; h_[0] = f2bf(v_); r_ = v_ - bf2f(h_[0]);                      \
    m_[0] = f2bf(r_); l_[0] = f2bf(r_ - bf2f(m_[0]));                         \
    v_ = VG_.y; h_[1] = f2bf(v_); r_ = v_ - bf2f(h_[1]);                      \
    m_[1] = f2bf(r_); l_[1] = f2bf(r_ - bf2f(m_[1]));                         \
    v_ = VG_.z; h_[2] = f2bf(v_); r_ = v_ - bf2f(h_[2]);                      \
    m_[2] = f2bf(r_); l_[2] = f2bf(r_ - bf2f(m_[2]));                         \
    v_ = VG_.w; h_[3] = f2bf(v_); r_ = v_ - bf2f(h_[3]);                      \
    m_[3] = f2bf(r_); l_[3] = f2bf(r_ - bf2f(m_[3]));                         \
    *(short4v*)&PH_[OFF_] = h_;                                               \
    *(short4v*)&PM_[OFF_] = m_;                                               \
    *(short4v*)&PL_[OFF_] = l_;                                               \
  } while (0)

__global__ __launch_bounds__(256, 3)
void router_main(const float* __restrict__ zn, const float* __restrict__ zs,
                 const float* __restrict__ zt, const float* __restrict__ nz,
                 const float* __restrict__ nr, const int* __restrict__ patches,
                 const float* __restrict__ M, const float* __restrict__ c,
                 float* __restrict__ out) {
  // 37.5 KB carved from one buffer; Ls (17.4 KB f32) aliases Xh/Xm after loop
  __shared__ __align__(16) char smem[38400];
  short* const Xh  = (short*)smem;                 // [128][40] bf16 hi  (10240 B)
  short* const Xm  = (short*)(smem + 10240);       // [128][40] bf16 mid
  short* const Xl  = (short*)(smem + 20480);       // [128][40] bf16 lo
  short* const Mhs = (short*)(smem + 30720);       // [32][40]           (2560 B)
  short* const Mms = (short*)(smem + 33280);       // [32][40]
  short* const Mls = (short*)(smem + 35840);       // [32][40]
  float* const Ls  = (float*)smem;                 // [128][34] f32 alias

  const int t = threadIdx.x;
  const int row0 = blockIdx.x * ROWS;
  const int sr = t >> 3;    // staging row / M row (0..31)
  const int sk4 = t & 7;    // staging k-quad
  const int lane = t & 63;
  const int w = t >> 6;     // wave 0..3 -> rows 32w..32w+31

  // big (hh) and small (hm,mh,hl,lh,mm) accumulators, folded to f64 per stage
  float4v aB00 = {0,0,0,0}, aB01 = {0,0,0,0}, aB10 = {0,0,0,0}, aB11 = {0,0,0,0};
  float4v aS00 = {0,0,0,0}, aS01 = {0,0,0,0}, aS10 = {0,0,0,0}, aS11 = {0,0,0,0};
  double d00[4], d01[4], d10[4], d11[4];
#pragma unroll
  for (int r = 0; r < 4; ++r) { d00[r] = 0.0; d01[r] = 0.0; d10[r] = 0.0; d11[r] = 0.0; }

  float4 xg0, xg1, xg2, xg3, mg;

  // fragment addresses: A lane = row(lane&15) + kgroup(lane>>4)*8 contiguous k
  const int aoff = (w * 32 + (lane & 15)) * XPB + (lane >> 4) * 8;
  const int boff = (lane & 15) * XPB + (lane >> 4) * 8;
  const int soff = sr * XPB + 4 * sk4;

  LOAD_STAGE(0);   // prologue

  for (int s = 0; s < 32; ++s) {
    __syncthreads();   // previous iteration's LDS reads done
    CVT3(xg0, Xh, Xm, Xl, soff);
    CVT3(xg1, Xh, Xm, Xl, soff + 32 * XPB);
    CVT3(xg2, Xh, Xm, Xl, soff + 64 * XPB);
    CVT3(xg3, Xh, Xm, Xl, soff + 96 * XPB);
    CVT3(mg, Mhs, Mms, Mls, soff);
    __syncthreads();

    // issue next stage's loads NOW: MFMA phase below hides HBM latency
    if (s < 31) LOAD_STAGE(s + 1);

    short8v ah0 = *(const short8v*)&Xh[aoff];
    short8v ah1 = *(const short8v*)&Xh[aoff + 16 * XPB];
    short8v am0 = *(const short8v*)&Xm[aoff];
    short8v am1 = *(const short8v*)&Xm[aoff + 16 * XPB];
    short8v al0 = *(const short8v*)&Xl[aoff];
    short8v al1 = *(const short8v*)&Xl[aoff + 16 * XPB];
    short8v bh0 = *(const short8v*)&Mhs[boff];
    short8v bh1 = *(const short8v*)&Mhs[boff + 16 * XPB];
    short8v bm0 = *(const short8v*)&Mms[boff];
    short8v bm1 = *(const short8v*)&Mms[boff + 16 * XPB];
    short8v bl0 = *(const short8v*)&Mls[boff];
    short8v bl1 = *(const short8v*)&Mls[boff + 16 * XPB];

    // hh into big acc (mirrors round-7's f32 chunk accumulation exactly)
    aB00 = __builtin_amdgcn_mfma_f32_16x16x32_bf16(ah0, bh0, aB00, 0, 0, 0);
    aB01 = __builtin_amdgcn_mfma_f32_16x16x32_bf16(ah0, bh1, aB01, 0, 0, 0);
    aB10 = __builtin_amdgcn_mfma_f32_16x16x32_bf16(ah1, bh0, aB10, 0, 0, 0);
    aB11 = __builtin_amdgcn_mfma_f32_16x16x32_bf16(ah1, bh1, aB11, 0, 0, 0);
    // 2^-9-scale cross terms into small acc
    aS00 = __builtin_amdgcn_mfma_f32_16x16x32_bf16(ah0, bm0, aS00, 0, 0, 0);
    aS01 = __builtin_amdgcn_mfma_f32_16x16x32_bf16(ah0, bm1, aS01, 0, 0, 0);
    aS10 = __builtin_amdgcn_mfma_f32_16x16x32_bf16(ah1, bm0, aS10, 0, 0, 0);
    aS11 = __builtin_amdgcn_mfma_f32_16x16x32_bf16(ah1, bm1, aS11, 0, 0, 0);
    aS00 = __builtin_amdgcn_mfma_f32_16x16x32_bf16(am0, bh0, aS00, 0, 0, 0);
    aS01 = __builtin_amdgcn_mfma_f32_16x16x32_bf16(am0, bh1, aS01, 0, 0, 0);
    aS10 = __builtin_amdgcn_mfma_f32_16x16x32_bf16(am1, bh0, aS10, 0, 0, 0);
    aS11 = __builtin_amdgcn_mfma_f32_16x16x32_bf16(am1, bh1, aS11, 0, 0, 0);
    // 2^-18-scale terms (dropping these was round-10's 1.4e-6 failure)
    aS00 = __builtin_amdgcn_mfma_f32_16x16x32_bf16(ah0, bl0, aS00, 0, 0, 0);
    aS01 = __builtin_amdgcn_mfma_f32_16x16x32_bf16(ah0, bl1, aS01, 0, 0, 0);
    aS10 = __builtin_amdgcn_mfma_f32_16x16x32_bf16(ah1, bl0, aS10, 0, 0, 0);
    aS11 = __builtin_amdgcn_mfma_f32_16x16x32_bf16(ah1, bl1, aS11, 0, 0, 0);
    aS00 = __builtin_amdgcn_mfma_f32_16x16x32_bf16(al0, bh0, aS00, 0, 0, 0);
    aS01 = __builtin_amdgcn_mfma_f32_16x16x32_bf16(al0, bh1, aS01, 0, 0, 0);
    aS10 = __builtin_amdgcn_mfma_f32_16x16x32_bf16(al1, bh0, aS10, 0, 0, 0);
    aS11 = __builtin_amdgcn_mfma_f32_16x16x32_bf16(al1, bh1, aS11, 0, 0, 0);
    aS00 = __builtin_amdgcn_mfma_f32_16x16x32_bf16(am0, bm0, aS00, 0, 0, 0);
    aS01 = __builtin_amdgcn_mfma_f32_16x16x32_bf16(am0, bm1, aS01, 0, 0, 0);
    aS10 = __builtin_amdgcn_mfma_f32_16x16x32_bf16(am1, bm0, aS10, 0, 0, 0);
    aS11 = __builtin_amdgcn_mfma_f32_16x16x32_bf16(am1, bm1, aS11, 0, 0, 0);

    // per-stage fold into f64 (keeps f32 partials at 32-k chunk scale = round-7 noise)
#pragma unroll
    for (int r = 0; r < 4; ++r) {
      d00[r] += (double)aB00[r] + (double)aS00[r]; aB00[r] = 0.f; aS00[r] = 0.f;
      d01[r] += (double)aB01[r] + (double)aS01[r]; aB01[r] = 0.f; aS01[r] = 0.f;
      d10[r] += (double)aB10[r] + (double)aS10[r]; aB10[r] = 0.f; aS10[r] = 0.f;
      d11[r] += (double)aB11[r] + (double)aS11[r]; aB11[r] = 0.f; aS11[r] = 0.f;
    }
  }

  __syncthreads();   // all frag reads complete before Ls (aliased) is written

  // C/D layout (m89-verified): col = lane&15 (= j from B), row = (lane>>4)*4+reg
  {
    const double c0 = (double)c[lane & 15];
    const double c1 = (double)c[16 + (lane & 15)];
    const int er = w * 32 + (lane >> 4) * 4;
    const int jc = lane & 15;
#pragma unroll
    for (int reg = 0; reg < 4; ++reg) {
      Ls[(er + reg) * LP + jc]           = (float)(d00[reg] + c0);
      Ls[(er + reg) * LP + 16 + jc]      = (float)(d01[reg] + c1);
      Ls[(er + 16 + reg) * LP + jc]      = (float)(d10[reg] + c0);
      Ls[(er + 16 + reg) * LP + 16 + jc] = (float)(d11[reg] + c1);
    }
  }
  __syncthreads();

  if (t < ROWS) {
    const int row = row0 + t;
    float L[32];
#pragma unroll
    for (int j = 0; j < 32; ++j) L[j] = Ls[t * LP + j];

    float nrv[16];
#pragma unroll
    for (int q = 0; q < 4; ++q) {
      float4 v = *(const float4*)&nr[(size_t)row * 16 + 4 * q];
      nrv[4 * q] = v.x; nrv[4 * q + 1] = v.y; nrv[4 * q + 2] = v.z; nrv[4 * q + 3] = v.w;
    }

    float lg[16];
#pragma unroll
    for (int p = 0; p < 16; ++p) {
      const float x = L[16 + p];
      const float sp = (x > 15.f) ? x : log1pf(expf(x));   // softplus
      lg[p] = L[p] + nrv[p] * sp;
    }

    float mx = lg[0];
#pragma unroll
    for (int p = 1; p < 16; ++p) mx = fmaxf(mx, lg[p]);
    float e[16]; float sum = 0.f;
#pragma unroll
    for (int p = 0; p < 16; ++p) { e[p] = expf(lg[p] - mx); sum += e[p]; }
    float w2[16];
#pragma unroll
    for (int p = 0; p < 16; ++p) w2[p] = e[p] / sum;

    // top-4, strict > scan => lowest index wins ties (jax.lax.top_k semantics)
    int idx[4]; float val[4]; unsigned used = 0;
#pragma unroll
    for (int kk = 0; kk < 4; ++kk) {
      float best = -1.f; int bi = 0;
#pragma unroll
      for (int p = 0; p < 16; ++p) {
        const bool ok = (((used >> p) & 1u) == 0u) && (w2[p] > best);
        best = ok ? w2[p] : best;
        bi = ok ? p : bi;
      }
      idx[kk] = bi; val[kk] = best; used |= (1u << bi);
    }

    float so[16];
#pragma unroll
    for (int p = 0; p < 16; ++p) {
      float v = 0.f;
#pragma unroll
      for (int kk = 0; kk < 4; ++kk) v = (idx[kk] == p) ? val[kk] : v;
      so[p] = v;
    }
#pragma unroll
    for (int q = 0; q < 4; ++q)
      *(float4*)&out[(size_t)row * 16 + 4 * q] =
          make_float4(so[4 * q], so[4 * q + 1], so[4 * q + 2], so[4 * q + 3]);

    float4 pv, iv;
    pv.x = (float)patches[idx[0]]; pv.y = (float)patches[idx[1]];
    pv.z = (float)patches[idx[2]]; pv.w = (float)patches[idx[3]];
    iv.x = (float)idx[0]; iv.y = (float)idx[1];
    iv.z = (float)idx[2]; iv.w = (float)idx[3];
    *(float4*)&out[(size_t)B_ROWS * 16 + (size_t)row * 4] = pv;
    *(float4*)&out[(size_t)B_ROWS * 20 + (size_t)row * 4] = iv;
  }
}

// ---------------- launcher ---------------------------------------------------
extern "C" void kernel_launch(void* const* d_in, const int* in_sizes, int n_in,
                              void* d_out, int out_size, void* d_ws, size_t ws_size,
                              hipStream_t stream) {
  const float* zn = (const float*)d_in[0];
  const float* zs = (const float*)d_in[1];
  const float* zt = (const float*)d_in[2];
  const float* nz = (const float*)d_in[3];
  const float* nr = (const float*)d_in[4];
  const int*   pc = (const int*)d_in[5];
  const float* Wp = (const float*)d_in[6];
  const float* bp = (const float*)d_in[7];
  const float* Wr = (const float*)d_in[8];
  const float* br = (const float*)d_in[9];
  const float* Wn = (const float*)d_in[10];
  const float* bn = (const float*)d_in[11];
  float* out = (float*)d_out;
  float* M = (float*)d_ws;            // 32*1024 floats (128 KB, known-safe ws size)
  float* c = M + 32 * 1024;           // 32 floats

  precompute_M<<<128, 256, 0, stream>>>(Wp, Wr, Wn, bp, br, bn, M, c);
  router_main<<<B_ROWS / ROWS, 256, 0, stream>>>(zn, zs, zt, nz, nr, pc, M, c, out);
}